// Round 9
// baseline (256.551 us; speedup 1.0000x reference)
//
#include <hip/hip_runtime.h>

#define BQ 4
#define SQ 2048
#define DQ 1024
#define HQ 16
#define BHQ 64

typedef __attribute__((ext_vector_type(8))) short short8;
typedef __attribute__((ext_vector_type(4))) float f32x4;
typedef __attribute__((ext_vector_type(16))) float f32x16;
typedef unsigned short u16;
typedef unsigned int u32;

__device__ __forceinline__ u16 f2bf(float f) {
  u32 u = __float_as_uint(f);
  u32 r = u + 0x7fffu + ((u >> 16) & 1u);
  return (u16)(r >> 16);
}
__device__ __forceinline__ float bf2f(u16 h) {
  return __uint_as_float(((u32)h) << 16);
}

// packed f32x2 -> bf16x2 (RNE), one instruction
__device__ __forceinline__ u32 pkbf(float lo, float hi_) {
  u32 r;
  asm("v_cvt_pk_bf16_f32 %0, %1, %2" : "=v"(r) : "v"(lo), "v"(hi_));
  return r;
}
// raw v_exp_f32: computes 2^x (input already in log2 domain)
__device__ __forceinline__ float fexp2(float x) {
  float r;
  asm("v_exp_f32 %0, %1" : "=v"(r) : "v"(x));
  return r;
}
// cross-half exchange via shfl (known-correct)
__device__ __forceinline__ float xmax32(float x) { return fmaxf(x, __shfl_xor(x, 32)); }
__device__ __forceinline__ float xsum32(float x) { return x + __shfl_xor(x, 32); }
__device__ __forceinline__ u32 xword(u32 send) { return (u32)__shfl_xor((int)send, 32); }

// async global->LDS, 16B per lane. LDS dest must be wave-uniform; HW adds lane*16.
__device__ __forceinline__ void gload_lds16(const void* g, void* l) {
  __builtin_amdgcn_global_load_lds(
      (const __attribute__((address_space(1))) u32*)(unsigned long long)g,
      (__attribute__((address_space(3))) u32*)(u32)(unsigned long long)l,
      16, 0, 0);
}

// ---------------- fp32 -> bf16 convert (vectorized) ----------------
__global__ __launch_bounds__(256) void k_cvt(const float* __restrict__ in, u16* __restrict__ out, int n4) {
  int i = blockIdx.x * 256 + threadIdx.x;
  if (i < n4) {
    float4 v = ((const float4*)in)[i];
    ushort4 o;
    o.x = f2bf(v.x); o.y = f2bf(v.y); o.z = f2bf(v.z); o.w = f2bf(v.w);
    ((ushort4*)out)[i] = o;
  }
}

// ---------------- transpose + convert: in[R][C] f32 -> out[C][R] bf16 ----------------
__global__ __launch_bounds__(256) void k_transpose_cvt(const float* __restrict__ in, u16* __restrict__ out,
                                                       int R, int C) {
  __shared__ float t[32][33];
  int c0 = blockIdx.x * 32, r0 = blockIdx.y * 32;
  int tx = threadIdx.x & 31, ty = threadIdx.x >> 5;
  for (int rr = ty; rr < 32; rr += 8)
    t[rr][tx] = in[(size_t)(r0 + rr) * C + c0 + tx];
  __syncthreads();
  for (int rr = ty; rr < 32; rr += 8)
    out[(size_t)(c0 + rr) * R + r0 + tx] = f2bf(t[tx][rr]);
}

// ---------------- RoPE cos/sin table [S][32][2] f32 ----------------
__global__ __launch_bounds__(256) void k_rope_table(float* __restrict__ tab) {
  int i = blockIdx.x * 256 + threadIdx.x;
  if (i >= SQ * 32) return;
  int s = i >> 5, dp = i & 31;
  float invf = expf(-0.28782313662425576f * (float)dp);
  float ang = (float)s * invf;
  tab[i * 2] = cosf(ang);
  tab[i * 2 + 1] = sinf(ang);
}

// ---------------- RoPE apply in-place on q (scaled, log2 domain) and k ----------------
__global__ __launch_bounds__(256) void k_rope(u16* __restrict__ q, u16* __restrict__ k,
                                              const float* __restrict__ tab) {
  int i = blockIdx.x * 256 + threadIdx.x;
  const int half = BHQ * SQ * 32;
  u16* buf = (i < half) ? q : k;
  float scale = (i < half) ? 0.125f * 1.44269504088896f : 1.0f;
  int rem = (i < half) ? i : i - half;
  int r = rem >> 5, dp = rem & 31;
  int s = r & (SQ - 1);
  float c = tab[(s * 32 + dp) * 2], sn = tab[(s * 32 + dp) * 2 + 1];
  size_t base = (size_t)r * 64 + dp;
  float a = bf2f(buf[base]), b = bf2f(buf[base + 32]);
  buf[base] = f2bf((a * c - b * sn) * scale);
  buf[base + 32] = f2bf((b * c + a * sn) * scale);
}

// ---------------- mask all-ones flags per 32-chunk: mflags[b*64+c] ----------------
__global__ __launch_bounds__(256) void k_mflags(const int* __restrict__ mask, int* __restrict__ mflags) {
  int tid = threadIdx.x;  // 256 = 4b * 64c
  int b = tid >> 6, c = tid & 63;
  int all1 = 1;
  for (int i = 0; i < 32; ++i) all1 &= (mask[b * SQ + c * 32 + i] != 0) ? 1 : 0;
  mflags[tid] = all1;
  if (tid == 0) mflags[256] = 1;  // pad for prefetch over-read
}

// ---------------- transpose v [bh][S][64] -> vTs tiled [bh][kt][64][32], slot-swizzled ----------------
__global__ __launch_bounds__(256) void k_transpose_v(const u16* __restrict__ v, u16* __restrict__ vTs) {
  __shared__ u16 t[64][72];
  int s0 = blockIdx.x * 64, bh = blockIdx.y;
  int tid = threadIdx.x;
  int row = tid >> 2, c0 = (tid & 3) * 16;
  const u16* src = v + ((size_t)bh * SQ + s0 + row) * 64 + c0;
  *(short8*)&t[row][c0] = *(const short8*)src;
  *(short8*)&t[row][c0 + 8] = *(const short8*)(src + 8);
  __syncthreads();
  u16 tmp[16];
#pragma unroll
  for (int i = 0; i < 16; i++) tmp[i] = t[c0 + i][row];  // V^T[row][s0+c0 .. +16]
  int kt = blockIdx.x * 2 + (c0 >> 5);
  int s_lo = (c0 & 31) >> 3;        // 0 or 2
  int g = (row >> 1) & 3;
  u16* base = vTs + (((size_t)(bh * 64 + kt) * 64 + row) * 32);
  *(short8*)(base + ((s_lo) ^ g) * 8) = *(short8*)&tmp[0];
  *(short8*)(base + ((s_lo + 1) ^ g) * 8) = *(short8*)&tmp[8];
}

// ---------------- GEMM: C[M,N] = A[M,K](bf16) @ Bt[N,K]^T(bf16) ----------------
template <int EPI>
__global__ __launch_bounds__(256) void k_gemm(const u16* __restrict__ A, const u16* __restrict__ Bt,
                                              float* __restrict__ Cf, u16* __restrict__ qb,
                                              u16* __restrict__ kb, u16* __restrict__ vb, int K) {
  __shared__ u16 lA[128 * 32];
  __shared__ u16 lB[128 * 32];
  int tid = threadIdx.x, w = tid >> 6, l = tid & 63;
  int wm = w >> 1, wn = w & 1;
  int tm = blockIdx.x, tn = blockIdx.y;
  int li = l & 15, lg = l >> 4;
  const u16* gA = A + (size_t)tm * 128 * K;
  const u16* gB = Bt + (size_t)tn * 128 * K;
  f32x4 acc[4][4];
#pragma unroll
  for (int i = 0; i < 4; i++)
#pragma unroll
    for (int j = 0; j < 4; j++) acc[i][j] = (f32x4){0.f, 0.f, 0.f, 0.f};
  int c0 = w, c1 = w + 4;
  int srow0 = c0 * 16 + (l >> 2), srow1 = c1 * 16 + (l >> 2);
  int scol = (l & 3) * 8;
  for (int kt = 0; kt < K; kt += 32) {
    __syncthreads();
    gload_lds16(gA + (size_t)srow0 * K + kt + scol, &lA[c0 * 512]);
    gload_lds16(gA + (size_t)srow1 * K + kt + scol, &lA[c1 * 512]);
    gload_lds16(gB + (size_t)srow0 * K + kt + scol, &lB[c0 * 512]);
    gload_lds16(gB + (size_t)srow1 * K + kt + scol, &lB[c1 * 512]);
    __syncthreads();
    short8 af[4], bfr[4];
#pragma unroll
    for (int mf = 0; mf < 4; ++mf) af[mf] = *(const short8*)&lA[(wm * 64 + mf * 16 + li) * 32 + lg * 8];
#pragma unroll
    for (int nf = 0; nf < 4; ++nf) bfr[nf] = *(const short8*)&lB[(wn * 64 + nf * 16 + li) * 32 + lg * 8];
#pragma unroll
    for (int mf = 0; mf < 4; ++mf)
#pragma unroll
      for (int nf = 0; nf < 4; ++nf)
        acc[mf][nf] = __builtin_amdgcn_mfma_f32_16x16x32_bf16(af[mf], bfr[nf], acc[mf][nf], 0, 0, 0);
  }
#pragma unroll
  for (int mf = 0; mf < 4; ++mf) {
    int mg0 = tm * 128 + wm * 64 + mf * 16 + lg * 4;
#pragma unroll
    for (int nf = 0; nf < 4; ++nf) {
      int ng = tn * 128 + wn * 64 + nf * 16 + li;
#pragma unroll
      for (int r = 0; r < 4; ++r) {
        float val = acc[mf][nf][r];
        int mg = mg0 + r;
        if (EPI == 0) {
          Cf[(size_t)mg * 1024 + ng] = val;
        } else {
          int b = mg >> 11, s = mg & 2047;
          int which = ng >> 10, hd6 = ng & 1023;
          int h = hd6 >> 6, d = hd6 & 63;
          u16* dst = which == 0 ? qb : (which == 1 ? kb : vb);
          dst[((((size_t)b * HQ + h) * SQ + s) << 6) + d] = f2bf(val);
        }
      }
    }
  }
}

// ---------------- flash attention v8: LDS-shared K/V, uniform blocks, 2 tiles/phase ----------------
// Block = 4 waves; processes super-tile qsup=p then qsup=15-p of ONE bh (68 k-trips
// for EVERY block -> zero drain). Per phase: stage 2 K-tiles + 2 V-tiles (16KB) via
// global_load_lds (double-buffered), 8 QK-MFMA, joint 32-value softmax, 8 PV-MFMA,
// ONE barrier. Swapped QK^T in-register softmax (log2 domain), verified layouts.
__global__ __launch_bounds__(256) void k_flash8(const u16* __restrict__ Q, const u16* __restrict__ Kb,
                                                const u16* __restrict__ VTs, const int* __restrict__ mask,
                                                const int* __restrict__ mflags, u16* __restrict__ O) {
  __shared__ alignas(16) u16 Kl[2][4096];  // [buf][tile*2048 + row*64 + d], rows source-swizzled
  __shared__ alignas(16) u16 Vl[2][4096];  // [buf][tile*2048 + d*32 + k], slot-swizzled
  int bid = blockIdx.x;
  int bh = (bid & 7) + 8 * ((bid >> 3) & 7);  // bh%8 pinned to XCD
  int p = bid >> 6;                            // 0..7
  int tid = threadIdx.x, w = tid >> 6, l = tid & 63;
  int j = l & 31, hi = l >> 5;
  int b = bh >> 4, h = bh & 15;
  const int* mp = mask + b * SQ + 4 * hi;
  const int* fp = mflags + b * 64;

  int sr = tid >> 3, sc16 = tid & 7;
  const u16* Kg0 = Kb + (size_t)bh * SQ * 64 + sr * 64 + ((sc16 ^ (sr & 7)) * 8);  // +kt*2048
  const u16* Vg0 = VTs + (size_t)bh * 64 * 2048 + tid * 8;                          // +kt*2048
  u16* KlB = &Kl[0][w * 512];  // wave-uniform quarter base; +tile*2048, +buf*4096 (u16)
  u16* VlB = &Vl[0][w * 512];
  int swK = j & 7, swV = (j >> 1) & 3;

  auto attn_pass = [&](int qsup) {
    int myqt = qsup * 4 + w;
    int qbase = myqt * 32;
    int P = 2 * qsup + 2;  // phases; nt = 4*qsup+4 tiles

    const u16* qp = Q + ((size_t)bh * SQ + qbase + j) * 64 + hi * 8;
    short8 qf[4];
#pragma unroll
    for (int kb = 0; kb < 4; ++kb) qf[kb] = *(const short8*)(qp + kb * 16);

    f32x16 o0, o1;
#pragma unroll
    for (int i = 0; i < 16; ++i) { o0[i] = 0.f; o1[i] = 0.f; }
    float mrun = -INFINITY, lrun = 0.f;

    // prologue: stage tiles 0,1 into buffer 0
    gload_lds16(Kg0, KlB);
    gload_lds16(Kg0 + 2048, KlB + 2048);
    gload_lds16(Vg0, VlB);
    gload_lds16(Vg0 + 2048, VlB + 2048);
    __syncthreads();

    for (int ph = 0; ph < P; ++ph) {
      int cur = ph & 1;
      if (ph + 1 < P) {
        const u16* kg = Kg0 + (size_t)(2 * ph + 2) * 2048;
        const u16* vg = Vg0 + (size_t)(2 * ph + 2) * 2048;
        u16* kd = KlB + (cur ^ 1) * 4096;
        u16* vd = VlB + (cur ^ 1) * 4096;
        gload_lds16(kg, kd);
        gload_lds16(kg + 2048, kd + 2048);
        gload_lds16(vg, vd);
        gload_lds16(vg + 2048, vd + 2048);
      }
      int t0i = 2 * ph, t1i = 2 * ph + 1;
      int fl0 = fp[t0i], fl1 = fp[t1i];
      const u16* Kc0 = &Kl[cur][0];
      const u16* Kc1 = &Kl[cur][2048];
      const u16* Vc0 = &Vl[cur][0];
      const u16* Vc1 = &Vl[cur][2048];

      short8 k0f[4], k1f[4];
#pragma unroll
      for (int kb = 0; kb < 4; ++kb) {
        k0f[kb] = *(const short8*)&Kc0[j * 64 + ((hi + 2 * kb) ^ swK) * 8];
        k1f[kb] = *(const short8*)&Kc1[j * 64 + ((hi + 2 * kb) ^ swK) * 8];
      }
      f32x16 s0, s1;
#pragma unroll
      for (int i = 0; i < 16; ++i) { s0[i] = 0.f; s1[i] = 0.f; }
      __builtin_amdgcn_s_setprio(1);
#pragma unroll
      for (int kb = 0; kb < 4; ++kb)
        s0 = __builtin_amdgcn_mfma_f32_32x32x16_bf16(k0f[kb], qf[kb], s0, 0, 0, 0);
#pragma unroll
      for (int kb = 0; kb < 4; ++kb)
        s1 = __builtin_amdgcn_mfma_f32_32x32x16_bf16(k1f[kb], qf[kb], s1, 0, 0, 0);
      __builtin_amdgcn_s_setprio(0);

      short8 va00 = *(const short8*)&Vc0[j * 32 + ((hi) ^ swV) * 8];
      short8 va01 = *(const short8*)&Vc0[j * 32 + ((hi + 2) ^ swV) * 8];
      short8 vb00 = *(const short8*)&Vc0[(j + 32) * 32 + ((hi) ^ swV) * 8];
      short8 vb01 = *(const short8*)&Vc0[(j + 32) * 32 + ((hi + 2) ^ swV) * 8];
      short8 va10 = *(const short8*)&Vc1[j * 32 + ((hi) ^ swV) * 8];
      short8 va11 = *(const short8*)&Vc1[j * 32 + ((hi + 2) ^ swV) * 8];
      short8 vb10 = *(const short8*)&Vc1[(j + 32) * 32 + ((hi) ^ swV) * 8];
      short8 vb11 = *(const short8*)&Vc1[(j + 32) * 32 + ((hi + 2) ^ swV) * 8];

      if (!fl0) {
#pragma unroll
        for (int rq = 0; rq < 4; ++rq) {
          int4 mv = *(const int4*)(mp + t0i * 32 + 8 * rq);
          if (!mv.x) s0[4 * rq + 0] = -INFINITY;
          if (!mv.y) s0[4 * rq + 1] = -INFINITY;
          if (!mv.z) s0[4 * rq + 2] = -INFINITY;
          if (!mv.w) s0[4 * rq + 3] = -INFINITY;
        }
      }
      if (!fl1) {
#pragma unroll
        for (int rq = 0; rq < 4; ++rq) {
          int4 mv = *(const int4*)(mp + t1i * 32 + 8 * rq);
          if (!mv.x) s1[4 * rq + 0] = -INFINITY;
          if (!mv.y) s1[4 * rq + 1] = -INFINITY;
          if (!mv.z) s1[4 * rq + 2] = -INFINITY;
          if (!mv.w) s1[4 * rq + 3] = -INFINITY;
        }
      }
      // causal
      if (t0i >= myqt) {
        if (t0i > myqt) {
#pragma unroll
          for (int i = 0; i < 16; ++i) s0[i] = -INFINITY;
        } else {
#pragma unroll
          for (int rq = 0; rq < 4; ++rq)
#pragma unroll
            for (int t = 0; t < 4; ++t)
              if (8 * rq + 4 * hi + t > j) s0[4 * rq + t] = -INFINITY;
        }
      }
      if (t1i >= myqt) {
        if (t1i > myqt) {
#pragma unroll
          for (int i = 0; i < 16; ++i) s1[i] = -INFINITY;
        } else {
#pragma unroll
          for (int rq = 0; rq < 4; ++rq)
#pragma unroll
            for (int t = 0; t < 4; ++t)
              if (8 * rq + 4 * hi + t > j) s1[4 * rq + t] = -INFINITY;
        }
      }

      // joint online softmax over 32 values (log2 domain)
      float t0 = fmaxf(fmaxf(fmaxf(s0[0], s0[1]), fmaxf(s0[2], s0[3])),
                       fmaxf(fmaxf(s0[4], s0[5]), fmaxf(s0[6], s0[7])));
      t0 = fmaxf(t0, fmaxf(fmaxf(fmaxf(s0[8], s0[9]), fmaxf(s0[10], s0[11])),
                           fmaxf(fmaxf(s0[12], s0[13]), fmaxf(s0[14], s0[15]))));
      float t1 = fmaxf(fmaxf(fmaxf(s1[0], s1[1]), fmaxf(s1[2], s1[3])),
                       fmaxf(fmaxf(s1[4], s1[5]), fmaxf(s1[6], s1[7])));
      t1 = fmaxf(t1, fmaxf(fmaxf(fmaxf(s1[8], s1[9]), fmaxf(s1[10], s1[11])),
                           fmaxf(fmaxf(s1[12], s1[13]), fmaxf(s1[14], s1[15]))));
      float tmx = fmaxf(t0, t1);
      if (!__all(tmx <= mrun + 8.0f)) {  // defer-max (T13)
        float tm2 = xmax32(tmx);
        float mn = fmaxf(fmaxf(mrun, tm2), -1e30f);
        float alpha = fexp2(mrun - mn);
        mrun = mn;
        lrun *= alpha;
#pragma unroll
        for (int i = 0; i < 16; ++i) { o0[i] *= alpha; o1[i] *= alpha; }
      }
      float ts = 0.f;
#pragma unroll
      for (int i = 0; i < 16; ++i) {
        float pv = fexp2(s0[i] - mrun);
        s0[i] = pv;
        ts += pv;
      }
#pragma unroll
      for (int i = 0; i < 16; ++i) {
        float pv = fexp2(s1[i] - mrun);
        s1[i] = pv;
        ts += pv;
      }
      lrun += ts;

      // pack both tiles' P^T into B fragments
      u32 pa[4], pb[4];
#pragma unroll
      for (int q2 = 0; q2 < 4; ++q2) {
        pa[q2] = pkbf(s0[4 * q2 + 0], s0[4 * q2 + 1]);
        pb[q2] = pkbf(s0[4 * q2 + 2], s0[4 * q2 + 3]);
      }
      u32 ya01 = xword(hi ? pa[0] : pa[1]);
      u32 yb01 = xword(hi ? pb[0] : pb[1]);
      u32 ya23 = xword(hi ? pa[2] : pa[3]);
      u32 yb23 = xword(hi ? pb[2] : pb[3]);
      union { short8 s8; u32 wd[4]; } f00, f01, f10, f11;
      f00.wd[0] = hi ? ya01 : pa[0];
      f00.wd[1] = hi ? yb01 : pb[0];
      f00.wd[2] = hi ? pa[1] : ya01;
      f00.wd[3] = hi ? pb[1] : yb01;
      f01.wd[0] = hi ? ya23 : pa[2];
      f01.wd[1] = hi ? yb23 : pb[2];
      f01.wd[2] = hi ? pa[3] : ya23;
      f01.wd[3] = hi ? pb[3] : yb23;
#pragma unroll
      for (int q2 = 0; q2 < 4; ++q2) {
        pa[q2] = pkbf(s1[4 * q2 + 0], s1[4 * q2 + 1]);
        pb[q2] = pkbf(s1[4 * q2 + 2], s1[4 * q2 + 3]);
      }
      ya01 = xword(hi ? pa[0] : pa[1]);
      yb01 = xword(hi ? pb[0] : pb[1]);
      ya23 = xword(hi ? pa[2] : pa[3]);
      yb23 = xword(hi ? pb[2] : pb[3]);
      f10.wd[0] = hi ? ya01 : pa[0];
      f10.wd[1] = hi ? yb01 : pb[0];
      f10.wd[2] = hi ? pa[1] : ya01;
      f10.wd[3] = hi ? pb[1] : yb01;
      f11.wd[0] = hi ? ya23 : pa[2];
      f11.wd[1] = hi ? yb23 : pb[2];
      f11.wd[2] = hi ? pa[3] : ya23;
      f11.wd[3] = hi ? pb[3] : yb23;

      // PV both tiles
      __builtin_amdgcn_s_setprio(1);
      o0 = __builtin_amdgcn_mfma_f32_32x32x16_bf16(va00, f00.s8, o0, 0, 0, 0);
      o0 = __builtin_amdgcn_mfma_f32_32x32x16_bf16(va01, f01.s8, o0, 0, 0, 0);
      o1 = __builtin_amdgcn_mfma_f32_32x32x16_bf16(vb00, f00.s8, o1, 0, 0, 0);
      o1 = __builtin_amdgcn_mfma_f32_32x32x16_bf16(vb01, f01.s8, o1, 0, 0, 0);
      o0 = __builtin_amdgcn_mfma_f32_32x32x16_bf16(va10, f10.s8, o0, 0, 0, 0);
      o0 = __builtin_amdgcn_mfma_f32_32x32x16_bf16(va11, f11.s8, o0, 0, 0, 0);
      o1 = __builtin_amdgcn_mfma_f32_32x32x16_bf16(vb10, f10.s8, o1, 0, 0, 0);
      o1 = __builtin_amdgcn_mfma_f32_32x32x16_bf16(vb11, f11.s8, o1, 0, 0, 0);
      __builtin_amdgcn_s_setprio(0);

      __syncthreads();
    }

    // epilogue
    float lfull = xsum32(lrun);
    float inv = 1.0f / lfull;
    u16* ob = O + ((size_t)b * SQ + qbase + j) * DQ + h * 64 + 4 * hi;
#pragma unroll
    for (int q2 = 0; q2 < 4; ++q2) {
#pragma unroll
      for (int e = 0; e < 2; ++e) {
        *(u32*)(ob + 8 * q2 + 2 * e) = pkbf(o0[4 * q2 + 2 * e] * inv, o0[4 * q2 + 2 * e + 1] * inv);
        *(u32*)(ob + 32 + 8 * q2 + 2 * e) = pkbf(o1[4 * q2 + 2 * e] * inv, o1[4 * q2 + 2 * e + 1] * inv);
      }
    }
  };

  attn_pass(p);
  attn_pass(15 - p);
}

extern "C" void kernel_launch(void* const* d_in, const int* in_sizes, int n_in,
                              void* d_out, int out_size, void* d_ws, size_t ws_size,
                              hipStream_t stream) {
  const float* x = (const float*)d_in[0];
  const int* mask = (const int*)d_in[1];
  const float* wqkv = (const float*)d_in[2];
  const float* wout = (const float*)d_in[3];
  float* out = (float*)d_out;
  char* ws = (char*)d_ws;

  u16* xb    = (u16*)(ws + 0);           // 16 MB
  u16* wqkvT = (u16*)(ws + 16777216);    // 6 MB  [3072][1024]
  u16* woutT = (u16*)(ws + 23068672);    // 2 MB  [1024][1024]
  u16* qbuf  = (u16*)(ws + 25165824);    // 16 MB [bh][S][64]
  u16* kbuf  = (u16*)(ws + 41943040);    // 16 MB
  u16* vbuf  = (u16*)(ws + 58720256);    // 16 MB
  u16* vTs   = (u16*)(ws + 75497472);    // 16 MB [bh][64 kt][64][32] slot-swizzled
  u16* attnb = (u16*)(ws + 92274688);    // 16 MB [B*S][1024]
  float* tab = (float*)(ws + 109051904); // 512 KB
  int* mflags = (int*)(ws + 109576192);  // 2 KB

  k_rope_table<<<256, 256, 0, stream>>>(tab);
  k_mflags<<<1, 256, 0, stream>>>(mask, mflags);
  k_cvt<<<8192, 256, 0, stream>>>(x, xb, 2097152);
  k_transpose_cvt<<<dim3(96, 32), 256, 0, stream>>>(wqkv, wqkvT, 1024, 3072);
  k_transpose_cvt<<<dim3(32, 32), 256, 0, stream>>>(wout, woutT, 1024, 1024);
  k_gemm<1><<<dim3(64, 24), 256, 0, stream>>>(xb, wqkvT, nullptr, qbuf, kbuf, vbuf, 1024);
  k_rope<<<32768, 256, 0, stream>>>(qbuf, kbuf, tab);
  k_transpose_v<<<dim3(32, 64), 256, 0, stream>>>(vbuf, vTs);
  k_flash8<<<512, 256, 0, stream>>>(qbuf, kbuf, vTs, mask, mflags, attnb);
  k_gemm<0><<<dim3(64, 8), 256, 0, stream>>>(attnb, woutT, out, nullptr, nullptr, nullptr, 1024);
}

// Round 10
// 228.176 us; speedup vs baseline: 1.1244x; 1.1244x over previous
//
#include <hip/hip_runtime.h>

#define BQ 4
#define SQ 2048
#define DQ 1024
#define HQ 16
#define BHQ 64

typedef __attribute__((ext_vector_type(8))) short short8;
typedef __attribute__((ext_vector_type(4))) float f32x4;
typedef __attribute__((ext_vector_type(16))) float f32x16;
typedef unsigned short u16;
typedef unsigned int u32;

__device__ __forceinline__ u16 f2bf(float f) {
  u32 u = __float_as_uint(f);
  u32 r = u + 0x7fffu + ((u >> 16) & 1u);
  return (u16)(r >> 16);
}
__device__ __forceinline__ float bf2f(u16 h) {
  return __uint_as_float(((u32)h) << 16);
}

// packed f32x2 -> bf16x2 (RNE), one instruction
__device__ __forceinline__ u32 pkbf(float lo, float hi_) {
  u32 r;
  asm("v_cvt_pk_bf16_f32 %0, %1, %2" : "=v"(r) : "v"(lo), "v"(hi_));
  return r;
}
// raw v_exp_f32: computes 2^x (input already in log2 domain)
__device__ __forceinline__ float fexp2(float x) {
  float r;
  asm("v_exp_f32 %0, %1" : "=v"(r) : "v"(x));
  return r;
}
// cross-half exchange via shfl (known-correct)
__device__ __forceinline__ float xmax32(float x) { return fmaxf(x, __shfl_xor(x, 32)); }
__device__ __forceinline__ float xsum32(float x) { return x + __shfl_xor(x, 32); }
__device__ __forceinline__ u32 xword(u32 send) { return (u32)__shfl_xor((int)send, 32); }

// async global->LDS, 16B per lane. LDS dest must be wave-uniform; HW adds lane*16.
__device__ __forceinline__ void gload_lds16(const void* g, void* l) {
  __builtin_amdgcn_global_load_lds(
      (const __attribute__((address_space(1))) u32*)(unsigned long long)g,
      (__attribute__((address_space(3))) u32*)(u32)(unsigned long long)l,
      16, 0, 0);
}

// ---------------- fp32 -> bf16 convert (vectorized) ----------------
__global__ __launch_bounds__(256) void k_cvt(const float* __restrict__ in, u16* __restrict__ out, int n4) {
  int i = blockIdx.x * 256 + threadIdx.x;
  if (i < n4) {
    float4 v = ((const float4*)in)[i];
    ushort4 o;
    o.x = f2bf(v.x); o.y = f2bf(v.y); o.z = f2bf(v.z); o.w = f2bf(v.w);
    ((ushort4*)out)[i] = o;
  }
}

// ---------------- transpose + convert: in[R][C] f32 -> out[C][R] bf16 ----------------
__global__ __launch_bounds__(256) void k_transpose_cvt(const float* __restrict__ in, u16* __restrict__ out,
                                                       int R, int C) {
  __shared__ float t[32][33];
  int c0 = blockIdx.x * 32, r0 = blockIdx.y * 32;
  int tx = threadIdx.x & 31, ty = threadIdx.x >> 5;
  for (int rr = ty; rr < 32; rr += 8)
    t[rr][tx] = in[(size_t)(r0 + rr) * C + c0 + tx];
  __syncthreads();
  for (int rr = ty; rr < 32; rr += 8)
    out[(size_t)(c0 + rr) * R + r0 + tx] = f2bf(t[tx][rr]);
}

// ---------------- RoPE cos/sin table [S][32][2] f32 ----------------
__global__ __launch_bounds__(256) void k_rope_table(float* __restrict__ tab) {
  int i = blockIdx.x * 256 + threadIdx.x;
  if (i >= SQ * 32) return;
  int s = i >> 5, dp = i & 31;
  float invf = expf(-0.28782313662425576f * (float)dp);
  float ang = (float)s * invf;
  tab[i * 2] = cosf(ang);
  tab[i * 2 + 1] = sinf(ang);
}

// ---------------- mask all-ones flags per 32-chunk: mflags[b*64+c] ----------------
__global__ __launch_bounds__(256) void k_mflags(const int* __restrict__ mask, int* __restrict__ mflags) {
  int tid = threadIdx.x;  // 256 = 4b * 64c
  int b = tid >> 6, c = tid & 63;
  int all1 = 1;
  for (int i = 0; i < 32; ++i) all1 &= (mask[b * SQ + c * 32 + i] != 0) ? 1 : 0;
  mflags[tid] = all1;
  if (tid == 0) mflags[256] = 1;  // pad for prefetch over-read
}

// ---------------- GEMM: C[M,N] = A[M,K](bf16) @ Bt[N,K]^T(bf16) ----------------
// EPI 0: write f32 C row-major. EPI 1 (QKV): fused epilogue —
//   q/k: RoPE applied in f32 (pairs acc[nf], acc[nf+2] = dims d, d+32), q scaled 0.125*log2e.
//   v: written directly to tiled slot-swizzled vTs [bh][kt][64 d][32 k].
template <int EPI>
__global__ __launch_bounds__(256) void k_gemm(const u16* __restrict__ A, const u16* __restrict__ Bt,
                                              float* __restrict__ Cf, u16* __restrict__ qb,
                                              u16* __restrict__ kb, u16* __restrict__ vTs,
                                              const float* __restrict__ tab, int K) {
  __shared__ u16 lA[128 * 32];
  __shared__ u16 lB[128 * 32];
  int tid = threadIdx.x, w = tid >> 6, l = tid & 63;
  int wm = w >> 1, wn = w & 1;
  int tm = blockIdx.x, tn = blockIdx.y;
  int li = l & 15, lg = l >> 4;
  const u16* gA = A + (size_t)tm * 128 * K;
  const u16* gB = Bt + (size_t)tn * 128 * K;
  f32x4 acc[4][4];
#pragma unroll
  for (int i = 0; i < 4; i++)
#pragma unroll
    for (int j = 0; j < 4; j++) acc[i][j] = (f32x4){0.f, 0.f, 0.f, 0.f};
  int c0 = w, c1 = w + 4;
  int srow0 = c0 * 16 + (l >> 2), srow1 = c1 * 16 + (l >> 2);
  int scol = (l & 3) * 8;
  for (int kt = 0; kt < K; kt += 32) {
    __syncthreads();
    gload_lds16(gA + (size_t)srow0 * K + kt + scol, &lA[c0 * 512]);
    gload_lds16(gA + (size_t)srow1 * K + kt + scol, &lA[c1 * 512]);
    gload_lds16(gB + (size_t)srow0 * K + kt + scol, &lB[c0 * 512]);
    gload_lds16(gB + (size_t)srow1 * K + kt + scol, &lB[c1 * 512]);
    __syncthreads();
    short8 af[4], bfr[4];
#pragma unroll
    for (int mf = 0; mf < 4; ++mf) af[mf] = *(const short8*)&lA[(wm * 64 + mf * 16 + li) * 32 + lg * 8];
#pragma unroll
    for (int nf = 0; nf < 4; ++nf) bfr[nf] = *(const short8*)&lB[(wn * 64 + nf * 16 + li) * 32 + lg * 8];
#pragma unroll
    for (int mf = 0; mf < 4; ++mf)
#pragma unroll
      for (int nf = 0; nf < 4; ++nf)
        acc[mf][nf] = __builtin_amdgcn_mfma_f32_16x16x32_bf16(af[mf], bfr[nf], acc[mf][nf], 0, 0, 0);
  }
  if (EPI == 0) {
#pragma unroll
    for (int mf = 0; mf < 4; ++mf) {
      int mg0 = tm * 128 + wm * 64 + mf * 16 + lg * 4;
#pragma unroll
      for (int nf = 0; nf < 4; ++nf) {
        int ng = tn * 128 + wn * 64 + nf * 16 + li;
#pragma unroll
        for (int r = 0; r < 4; ++r)
          Cf[(size_t)(mg0 + r) * 1024 + ng] = acc[mf][nf][r];
      }
    }
  } else {
    int which = tn >> 3;                 // 0=q 1=k 2=v (128-col tiles, 8 per matrix)
    int h = (tn & 7) * 2 + wn;           // head
#pragma unroll
    for (int mf = 0; mf < 4; ++mf) {
#pragma unroll
      for (int r = 0; r < 4; ++r) {
        int mg = tm * 128 + wm * 64 + mf * 16 + lg * 4 + r;
        int b = mg >> 11, s = mg & 2047;
        if (which < 2) {
          float scale = (which == 0) ? 0.125f * 1.44269504088896f : 1.0f;
          u16* dst = (which == 0 ? qb : kb) + ((((size_t)b * HQ + h) * SQ + s) << 6);
#pragma unroll
          for (int nf2 = 0; nf2 < 2; ++nf2) {
            int dp = nf2 * 16 + li;      // 0..31
            float c = tab[(s * 32 + dp) * 2];
            float sn = tab[(s * 32 + dp) * 2 + 1];
            float a = acc[mf][nf2][r];
            float bb = acc[mf][nf2 + 2][r];
            dst[dp] = f2bf((a * c - bb * sn) * scale);
            dst[dp + 32] = f2bf((bb * c + a * sn) * scale);
          }
        } else {
          int kt = s >> 5, kk = s & 31;
          size_t tb = (((size_t)(b * HQ + h) * 64 + kt) * 64);
#pragma unroll
          for (int nf = 0; nf < 4; ++nf) {
            int d = nf * 16 + li;
            int addr = (((kk >> 3) ^ ((d >> 1) & 3)) << 3) + (kk & 7);
            vTs[(tb + d) * 32 + addr] = f2bf(acc[mf][nf][r]);
          }
        }
      }
    }
  }
}

// ---------------- flash attention v7 (93us verified): LDS-shared K/V, swapped QK^T ----------------
// Block = 4 waves on q-tiles {qsup*4 .. qsup*4+3} of ONE bh. Per k-tile the block stages
// K (4KB, source-swizzled) + V^T (4KB, pre-swizzled tiled layout) via global_load_lds,
// double-buffered, one barrier per tile. CU-balanced qsup quad {v,7-v,8+v,15-v} (sum 30).
__global__ __launch_bounds__(256) void k_flash7(const u16* __restrict__ Q, const u16* __restrict__ Kb,
                                                const u16* __restrict__ VTs, const int* __restrict__ mask,
                                                const int* __restrict__ mflags, u16* __restrict__ O) {
  __shared__ alignas(16) u16 Kl[2][2048];
  __shared__ alignas(16) u16 Vl[2][2048];
  int bid = blockIdx.x;
  int bh = bid & 63;
  int u = bid >> 6, v = u & 3, k4 = u >> 2;
  int qsup = (k4 == 0) ? v : (k4 == 1) ? 7 - v : (k4 == 2) ? 8 + v : 15 - v;
  int tid = threadIdx.x, w = tid >> 6, l = tid & 63;
  int j = l & 31, hi = l >> 5;
  int myqt = qsup * 4 + w;
  int nt = qsup * 4 + 4;
  int b = bh >> 4, h = bh & 15;
  const int* mp = mask + b * SQ + 4 * hi;
  const int* fp = mflags + b * 64;

  // staging source addresses (per-thread)
  int sr = tid >> 3, sc16 = tid & 7;
  const u16* Kg0 = Kb + ((size_t)bh * SQ) * 64 + sr * 64 + ((sc16 ^ (sr & 7)) * 8);  // + kt*2048
  const u16* Vg0 = VTs + ((size_t)bh * 64) * 2048 + tid * 8;                          // + kt*2048
  u16* KlB = &Kl[0][(size_t)w * 512];  // wave-uniform dest bases (buffer toggled by +2048/4096B)
  u16* VlB = &Vl[0][(size_t)w * 512];

  // Q fragments (B operand)
  int qbase = myqt * 32;
  const u16* qp = Q + ((size_t)bh * SQ + qbase + j) * 64 + hi * 8;
  short8 qf[4];
#pragma unroll
  for (int kb = 0; kb < 4; ++kb) qf[kb] = *(const short8*)(qp + kb * 16);

  f32x16 o0, o1;
#pragma unroll
  for (int i = 0; i < 16; ++i) { o0[i] = 0.f; o1[i] = 0.f; }
  float mrun = -INFINITY, lrun = 0.f;

  int swK = (j & 7), swV = (j >> 1) & 3;
  int fl = fp[0];

  // prologue: stage tile 0 into buffer 0
  gload_lds16(Kg0, KlB);
  gload_lds16(Vg0, VlB);
  __syncthreads();

  for (int kt = 0; kt < nt; ++kt) {
    int cur = kt & 1;
    if (kt + 1 < nt) {  // stage next tile into other buffer
      gload_lds16(Kg0 + (size_t)(kt + 1) * 2048, KlB + (cur ^ 1) * 2048);
      gload_lds16(Vg0 + (size_t)(kt + 1) * 2048, VlB + (cur ^ 1) * 2048);
    }
    int fln = fp[kt + 1];

    const u16* Kc = Kl[cur];
    const u16* Vc = Vl[cur];

    short8 kcf[4];
#pragma unroll
    for (int kb = 0; kb < 4; ++kb)
      kcf[kb] = *(const short8*)&Kc[j * 64 + (((hi + 2 * kb)) ^ swK) * 8];

    f32x16 s;
#pragma unroll
    for (int i = 0; i < 16; ++i) s[i] = 0.f;
    __builtin_amdgcn_s_setprio(1);
#pragma unroll
    for (int kb = 0; kb < 4; ++kb)
      s = __builtin_amdgcn_mfma_f32_32x32x16_bf16(kcf[kb], qf[kb], s, 0, 0, 0);
    __builtin_amdgcn_s_setprio(0);

    // V fragments for this tile (LDS; scheduled early by compiler)
    short8 va0 = *(const short8*)&Vc[j * 32 + ((hi) ^ swV) * 8];
    short8 va1 = *(const short8*)&Vc[j * 32 + ((hi + 2) ^ swV) * 8];
    short8 vb0 = *(const short8*)&Vc[(j + 32) * 32 + ((hi) ^ swV) * 8];
    short8 vb1 = *(const short8*)&Vc[(j + 32) * 32 + ((hi + 2) ^ swV) * 8];

    // pad mask: only when this 32-chunk has zeros (never in this harness)
    if (!fl) {
#pragma unroll
      for (int rq = 0; rq < 4; ++rq) {
        int4 mv = *(const int4*)(mp + kt * 32 + 8 * rq);
        if (!mv.x) s[4 * rq + 0] = -INFINITY;
        if (!mv.y) s[4 * rq + 1] = -INFINITY;
        if (!mv.z) s[4 * rq + 2] = -INFINITY;
        if (!mv.w) s[4 * rq + 3] = -INFINITY;
      }
    }
    fl = fln;
    // causal: diagonal tile masks k>q; tiles beyond own diagonal are fully masked
    if (kt >= myqt) {
      if (kt > myqt) {
#pragma unroll
        for (int i = 0; i < 16; ++i) s[i] = -INFINITY;
      } else {
#pragma unroll
        for (int rq = 0; rq < 4; ++rq)
#pragma unroll
          for (int t = 0; t < 4; ++t)
            if (8 * rq + 4 * hi + t > j) s[4 * rq + t] = -INFINITY;
      }
    }

    // online softmax in log2 domain, fully in-register
    float t0 = fmaxf(fmaxf(fmaxf(s[0], s[1]), fmaxf(s[2], s[3])),
                     fmaxf(fmaxf(s[4], s[5]), fmaxf(s[6], s[7])));
    t0 = fmaxf(t0, fmaxf(fmaxf(fmaxf(s[8], s[9]), fmaxf(s[10], s[11])),
                         fmaxf(fmaxf(s[12], s[13]), fmaxf(s[14], s[15]))));
    if (!__all(t0 <= mrun + 8.0f)) {  // defer-max (T13)
      float tm2 = xmax32(t0);
      float mn = fmaxf(fmaxf(mrun, tm2), -1e30f);
      float alpha = fexp2(mrun - mn);
      mrun = mn;
      lrun *= alpha;
#pragma unroll
      for (int i = 0; i < 16; ++i) { o0[i] *= alpha; o1[i] *= alpha; }
    }
    float ts = 0.f;
#pragma unroll
    for (int i = 0; i < 16; ++i) {
      float pv = fexp2(s[i] - mrun);
      s[i] = pv;
      ts += pv;
    }
    lrun += ts;

    // pack P^T into B fragments: cvt_pk pairs + one cross-half shfl per word-pair
    u32 pa[4], pb[4];
#pragma unroll
    for (int q2 = 0; q2 < 4; ++q2) {
      pa[q2] = pkbf(s[4 * q2 + 0], s[4 * q2 + 1]);
      pb[q2] = pkbf(s[4 * q2 + 2], s[4 * q2 + 3]);
    }
    u32 ya01 = xword(hi ? pa[0] : pa[1]);
    u32 yb01 = xword(hi ? pb[0] : pb[1]);
    u32 ya23 = xword(hi ? pa[2] : pa[3]);
    u32 yb23 = xword(hi ? pb[2] : pb[3]);
    union { short8 s8; u32 wd[4]; } f0, f1;
    f0.wd[0] = hi ? ya01 : pa[0];
    f0.wd[1] = hi ? yb01 : pb[0];
    f0.wd[2] = hi ? pa[1] : ya01;
    f0.wd[3] = hi ? pb[1] : yb01;
    f1.wd[0] = hi ? ya23 : pa[2];
    f1.wd[1] = hi ? yb23 : pb[2];
    f1.wd[2] = hi ? pa[3] : ya23;
    f1.wd[3] = hi ? pb[3] : yb23;

    // PV: O^T += V^T(frag A) x P^T(frag B)
    __builtin_amdgcn_s_setprio(1);
    o0 = __builtin_amdgcn_mfma_f32_32x32x16_bf16(va0, f0.s8, o0, 0, 0, 0);
    o0 = __builtin_amdgcn_mfma_f32_32x32x16_bf16(va1, f1.s8, o0, 0, 0, 0);
    o1 = __builtin_amdgcn_mfma_f32_32x32x16_bf16(vb0, f0.s8, o1, 0, 0, 0);
    o1 = __builtin_amdgcn_mfma_f32_32x32x16_bf16(vb1, f1.s8, o1, 0, 0, 0);
    __builtin_amdgcn_s_setprio(0);

    __syncthreads();  // drains vmem (next stage) + all waves done reading cur
  }

  // epilogue: merge the two halves' lrun, store q rows
  float lfull = xsum32(lrun);
  float inv = 1.0f / lfull;
  u16* ob = O + ((size_t)b * SQ + qbase + j) * DQ + h * 64 + 4 * hi;
#pragma unroll
  for (int q2 = 0; q2 < 4; ++q2) {
#pragma unroll
    for (int e = 0; e < 2; ++e) {
      *(u32*)(ob + 8 * q2 + 2 * e) = pkbf(o0[4 * q2 + 2 * e] * inv, o0[4 * q2 + 2 * e + 1] * inv);
      *(u32*)(ob + 32 + 8 * q2 + 2 * e) = pkbf(o1[4 * q2 + 2 * e] * inv, o1[4 * q2 + 2 * e + 1] * inv);
    }
  }
}

extern "C" void kernel_launch(void* const* d_in, const int* in_sizes, int n_in,
                              void* d_out, int out_size, void* d_ws, size_t ws_size,
                              hipStream_t stream) {
  const float* x = (const float*)d_in[0];
  const int* mask = (const int*)d_in[1];
  const float* wqkv = (const float*)d_in[2];
  const float* wout = (const float*)d_in[3];
  float* out = (float*)d_out;
  char* ws = (char*)d_ws;

  u16* xb    = (u16*)(ws + 0);           // 16 MB
  u16* wqkvT = (u16*)(ws + 16777216);    // 6 MB  [3072][1024]
  u16* woutT = (u16*)(ws + 23068672);    // 2 MB  [1024][1024]
  u16* qbuf  = (u16*)(ws + 25165824);    // 16 MB [bh][S][64]
  u16* kbuf  = (u16*)(ws + 41943040);    // 16 MB
  u16* vTs   = (u16*)(ws + 75497472);    // 16 MB [bh][64 kt][64][32] slot-swizzled
  u16* attnb = (u16*)(ws + 92274688);    // 16 MB [B*S][1024]
  float* tab = (float*)(ws + 109051904); // 512 KB
  int* mflags = (int*)(ws + 109576192);  // 2 KB

  k_rope_table<<<256, 256, 0, stream>>>(tab);
  k_mflags<<<1, 256, 0, stream>>>(mask, mflags);
  k_cvt<<<8192, 256, 0, stream>>>(x, xb, 2097152);
  k_transpose_cvt<<<dim3(96, 32), 256, 0, stream>>>(wqkv, wqkvT, 1024, 3072);
  k_transpose_cvt<<<dim3(32, 32), 256, 0, stream>>>(wout, woutT, 1024, 1024);
  k_gemm<1><<<dim3(64, 24), 256, 0, stream>>>(xb, wqkvT, nullptr, qbuf, kbuf, vTs, tab, 1024);
  k_flash7<<<1024, 256, 0, stream>>>(qbuf, kbuf, vTs, mask, mflags, attnb);
  k_gemm<0><<<dim3(64, 8), 256, 0, stream>>>(attnb, woutT, out, nullptr, nullptr, nullptr, nullptr, 1024);
}